// Round 8
// baseline (918.535 us; speedup 1.0000x reference)
//
#include <hip/hip_runtime.h>
#include <hip/hip_fp16.h>

// CRF mean-field, NHWC. Per iter: out = x + sw * blurW(blurH(softmax_C(xc)))
//
// R8 = R7 + TA-pressure fix on softmax input:
//  P1 (new): coalesced float4 halo staging (3024 chunks, 16B/lane; ~756
//      cache-line touches/block vs 10.4K for R7's 21 scalar loads/pixel)
//      scattered into planar fp16 LDS via the proven incremental
//      channel-walk (4 b16 writes per chunk).
//  P2: softmax now reads planar LDS (11 aligned b32/pixel; code proven
//      correct in R6 run), f32 math, writes probabilities in place.
//  P3/P4: packed v_pk_fma_f16 blurs, in place (unchanged, proven).
//  P5: float4 unary+out, planar b16 gather walk (unchanged, proven R7).
//  XCD bijective swizzle (unchanged, proven R7: FETCH 244->194 MB).
//
// R5 failed this idea with 12096 scalar staging loads (VALU-bound);
// this uses 4x fewer wave-instructions, all coalesced, walk-based scatter.
//
// In-place safety: P2 pixel-private, P3 column-private, P4 row-private
// (all taps in registers before writes); 4 barriers total.

#define BB    16
#define Himg  384
#define Wimg  384
#define CC    21
#define NP    11                   // channel pairs (last = c20 + zero pad)
#define TH    16
#define TW    16
#define RR    4
#define PH    (TH + 2*RR)          // 24
#define PW    (TW + 2*RR)          // 24
#define NPIX  (PH * PW)            // 576
#define PLANE_B 2384               // plane stride bytes (2304 + 80 pad; /4 %32 = 20)
#define ROW_B   (PW * 4)           // 96 B per plane row (24 slots)
#define NTASK (PW * NP)            // 264 (col, plane) tasks
#define RCHUNKS (TW * CC / 4)      // 84 float4 per tile row
#define NCHUNK5 (TH * RCHUNKS)     // 1344 output chunks
#define CHUNKS_ROW (PW * CC / 4)   // 126 float4 per halo row
#define NCHUNK1 (PH * CHUNKS_ROW)  // 3024 staging chunks
#define NTOT  (BB * Himg * Wimg * CC)  // 49545216
#define NTILES  (24 * 24 * BB)     // 9216

static __device__ __forceinline__ unsigned int pk_add(unsigned int a, unsigned int b) {
    unsigned int d; asm("v_pk_add_f16 %0, %1, %2" : "=v"(d) : "v"(a), "v"(b)); return d;
}
static __device__ __forceinline__ unsigned int pk_mul(unsigned int a, unsigned int b) {
    unsigned int d; asm("v_pk_mul_f16 %0, %1, %2" : "=v"(d) : "v"(a), "v"(b)); return d;
}
static __device__ __forceinline__ unsigned int pk_fma(unsigned int a, unsigned int b, unsigned int c) {
    unsigned int d; asm("v_pk_fma_f16 %0, %1, %2, %3" : "=v"(d) : "v"(a), "v"(b), "v"(c)); return d;
}

__global__ __launch_bounds__(256, 6)
void crf_iter_kernel(const float* __restrict__ xin,
                     const float* __restrict__ unary,
                     float* __restrict__ out,
                     const float* __restrict__ spacings,
                     const float* __restrict__ inv_theta,
                     const float* __restrict__ sw_ptr)
{
    __shared__ __align__(16) unsigned char smem[NP * PLANE_B];  // 26224 B

    const int tid = threadIdx.x;

    // ---- XCD-aware bijective swizzle: each XCD gets 1152 contiguous tiles ----
    const int lin = blockIdx.x + 24 * (blockIdx.y + 24 * blockIdx.z);
    const int swz = (lin & 7) * (NTILES / 8) + (lin >> 3);
    const int b   = swz / 576;
    const int rem = swz - b * 576;
    const int ty  = rem / 24;
    const int h0  = ty * TH;
    const int w0  = (rem - ty * 24) * TW;

    const float sp_h = spacings[b * 2 + 0];
    const float sp_w = spacings[b * 2 + 1];
    const float ith  = inv_theta[0];
    const float itw  = inv_theta[1];
    const float sw   = sw_ptr[0];
    // symmetric taps: k[i] == k[8-i]; center (i==4) excluded. Keep 4 each.
    unsigned int khp[4], kwp[4];
#pragma unroll
    for (int i = 0; i < 4; ++i) {
        float dh = sp_h * (float)(i - 4) * ith;
        float dw = sp_w * (float)(i - 4) * itw;
        float kh = __expf(-0.5f * dh * dh);
        float kw = sw * __expf(-0.5f * dw * dw);   // fold sw into horizontal
        __half2 a = __floats2half2_rn(kh, kh);
        __half2 c = __floats2half2_rn(kw, kw);
        khp[i] = *(unsigned int*)&a;
        kwp[i] = *(unsigned int*)&c;
    }

    // ---- Phase 1: coalesced float4 halo staging -> planar fp16 scatter ----
    // Lanes own consecutive 16B chunks of a halo row (2016B): fully
    // coalesced. Row-OOB rows skipped (stale LDS, P2 zeroes). Col-OOB
    // lanes load clamped garbage (finite), P2 zeroes those pixels.
    {
        const int rowbase = ((b * Himg + (h0 - RR)) * Wimg + (w0 - RR)) * CC;
        for (int idx = tid; idx < NCHUNK1; idx += 256) {   // 12 iters
            const int r  = idx / CHUNKS_ROW;
            const int q  = idx - r * CHUNKS_ROW;
            const int hh = h0 - RR + r;
            if (hh >= 0 && hh < Himg) {
                int basef = rowbase + r * (Wimg * CC) + q * 4;
                int a = basef < 0 ? 0 : (basef > NTOT - 4 ? NTOT - 4 : basef);
                const float4 v = *(const float4*)(xin + a);
                // scatter 4 consecutive row-floats (px,c) into planes
                const int f = q * 4;                 // row-float offset
                int px = f / CC;
                int c  = f - px * CC;
                int addr = (c >> 1) * PLANE_B + r * ROW_B + px * 4 + (c & 1) * 2;
                float vv[4];
                vv[0] = v.x; vv[1] = v.y; vv[2] = v.z; vv[3] = v.w;
#pragma unroll
                for (int i = 0; i < 4; ++i) {
                    *(__half*)(smem + addr) = __float2half_rn(vv[i]);
                    const int wrap = (c == 20);
                    const int odd  = c & 1;
                    addr += wrap ? (4 - 10 * PLANE_B) : (odd ? (PLANE_B - 2) : 2);
                    c = wrap ? 0 : c + 1;
                }
            }
        }
    }
    __syncthreads();

    // ---- Phase 2: f32 softmax over C from planar LDS, in place ----
    for (int p = tid; p < NPIX; p += 256) {
        const int r  = p / PW;
        const int px = p - r * PW;
        const int hh = h0 - RR + r;
        const int gw = w0 - RR + px;
        unsigned char* lbase = smem + p * 4;   // p*4 == r*ROW_B + px*4
        if (hh >= 0 && hh < Himg && gw >= 0 && gw < Wimg) {
            float v[22];
#pragma unroll
            for (int cp = 0; cp < NP; ++cp) {
                float2 f = __half22float2(*(const __half2*)(lbase + cp * PLANE_B));
                v[2*cp] = f.x; v[2*cp+1] = f.y;   // v[21] = pad garbage, unused
            }
            float m = v[0];
#pragma unroll
            for (int c = 1; c < CC; ++c) m = fmaxf(m, v[c]);
            float s = 0.f;
#pragma unroll
            for (int c = 0; c < CC; ++c) { v[c] = __expf(v[c] - m); s += v[c]; }
            const float inv = 1.0f / s;
#pragma unroll
            for (int cp = 0; cp < 10; ++cp)
                *(__half2*)(lbase + cp * PLANE_B) =
                    __floats2half2_rn(v[2*cp] * inv, v[2*cp+1] * inv);
            *(__half2*)(lbase + 10 * PLANE_B) = __floats2half2_rn(v[20] * inv, 0.f);
        } else {
            const __half2 z = __floats2half2_rn(0.f, 0.f);
#pragma unroll
            for (int cp = 0; cp < NP; ++cp)
                *(__half2*)(lbase + cp * PLANE_B) = z;
        }
    }
    __syncthreads();

    // ---- Phase 3: vertical blur, packed fp16, in place (rows 0..15) ----
    for (int t = tid; t < NTASK; t += 256) {
        const int cp  = t / PW;
        const int col = t - cp * PW;
        unsigned char* base = smem + cp * PLANE_B + col * 4;
        unsigned int v[PH];
#pragma unroll
        for (int r = 0; r < PH; ++r) v[r] = *(const unsigned int*)(base + r * ROW_B);
#pragma unroll
        for (int tt = 0; tt < TH; ++tt) {
            unsigned int s0 = pk_add(v[tt],     v[tt + 8]);
            unsigned int s1 = pk_add(v[tt + 1], v[tt + 7]);
            unsigned int s2 = pk_add(v[tt + 2], v[tt + 6]);
            unsigned int s3 = pk_add(v[tt + 3], v[tt + 5]);
            unsigned int acc = pk_mul(khp[0], s0);
            acc = pk_fma(khp[1], s1, acc);
            acc = pk_fma(khp[2], s2, acc);
            acc = pk_fma(khp[3], s3, acc);
            *(unsigned int*)(base + tt * ROW_B) = acc;
        }
    }
    __syncthreads();

    // ---- Phase 4: horizontal blur * sw, b128 rows, in place (cols 0..15) ----
    if (tid < TH * NP) {                   // 176 tasks
        const int h  = tid / NP;
        const int cp = tid - h * NP;
        unsigned char* base = smem + cp * PLANE_B + h * ROW_B;
        unsigned int v[PW];
#pragma unroll
        for (int k = 0; k < 6; ++k) {
            const uint4 q = *(const uint4*)(base + k * 16);
            v[4*k+0] = q.x; v[4*k+1] = q.y; v[4*k+2] = q.z; v[4*k+3] = q.w;
        }
        unsigned int o[TW];
#pragma unroll
        for (int wt = 0; wt < TW; ++wt) {
            unsigned int s0 = pk_add(v[wt],     v[wt + 8]);
            unsigned int s1 = pk_add(v[wt + 1], v[wt + 7]);
            unsigned int s2 = pk_add(v[wt + 2], v[wt + 6]);
            unsigned int s3 = pk_add(v[wt + 3], v[wt + 5]);
            unsigned int acc = pk_mul(kwp[0], s0);
            acc = pk_fma(kwp[1], s1, acc);
            acc = pk_fma(kwp[2], s2, acc);
            acc = pk_fma(kwp[3], s3, acc);
            o[wt] = acc;
        }
#pragma unroll
        for (int k = 0; k < 4; ++k) {
            uint4 wq;
            wq.x = o[4*k+0]; wq.y = o[4*k+1]; wq.z = o[4*k+2]; wq.w = o[4*k+3];
            *(uint4*)(base + k * 16) = wq;
        }
    }
    __syncthreads();

    // ---- Phase 5: out = unary + s, float4 I/O, planar b16 walk ----
    {
        const int gbase = ((b * Himg + h0) * Wimg + w0) * CC;
        for (int j = tid; j < NCHUNK5; j += 256) {
            const int hrow = j / RCHUNKS;
            const int qq   = j - hrow * RCHUNKS;
            const int f    = qq * 4;
            int px = f / 21;
            int c  = f - px * 21;
            int addr = (c >> 1) * PLANE_B + hrow * ROW_B + px * 4 + (c & 1) * 2;
            float sv[4];
#pragma unroll
            for (int i = 0; i < 4; ++i) {
                sv[i] = __half2float(*(const __half*)(smem + addr));
                const int wrap = (c == 20);
                const int odd  = c & 1;
                addr += wrap ? (4 - 10 * PLANE_B) : (odd ? (PLANE_B - 2) : 2);
                c = wrap ? 0 : c + 1;
            }
            const int g = gbase + hrow * (Wimg * CC) + f;
            const float4 u = *(const float4*)(unary + g);
            float4 o;
            o.x = u.x + sv[0]; o.y = u.y + sv[1];
            o.z = u.z + sv[2]; o.w = u.w + sv[3];
            *(float4*)(out + g) = o;
        }
    }
}

extern "C" void kernel_launch(void* const* d_in, const int* in_sizes, int n_in,
                              void* d_out, int out_size, void* d_ws, size_t ws_size,
                              hipStream_t stream) {
    const float* x         = (const float*)d_in[0];
    const float* spacings  = (const float*)d_in[1];
    const float* sw        = (const float*)d_in[2];
    const float* inv_theta = (const float*)d_in[3];
    float* out = (float*)d_out;
    float* ws  = (float*)d_ws;

    dim3 grid(Wimg / TW, Himg / TH, BB);   // 24 x 24 x 16 = 9216 blocks
    dim3 block(256);

    crf_iter_kernel<<<grid, block, 0, stream>>>(x,   x, out, spacings, inv_theta, sw);
    crf_iter_kernel<<<grid, block, 0, stream>>>(out, x, ws,  spacings, inv_theta, sw);
    crf_iter_kernel<<<grid, block, 0, stream>>>(ws,  x, out, spacings, inv_theta, sw);
    crf_iter_kernel<<<grid, block, 0, stream>>>(out, x, ws,  spacings, inv_theta, sw);
    crf_iter_kernel<<<grid, block, 0, stream>>>(ws,  x, out, spacings, inv_theta, sw);
}